// Round 13
// baseline (737.249 us; speedup 1.0000x reference)
//
#include <hip/hip_runtime.h>
#include <hip/hip_bf16.h>
#include <stdint.h>

// LLaMA block on MI355X. All matmuls in bf16 MFMA (16x16x32), fp32 accumulate.
// Dims fixed: B=2, S=2048, D=2048, H=16, hd=128, FF=5632.
// gemm256 (attempt 3): m201 geometry — regions are M-halves [128][64] bf16
// (128B row stride, gemm_bt's proven XOR swizzle). R4/R6 failed because the
// regions were K-halves ([256][32], 64B stride) -> 8-way bank conflicts.

typedef __attribute__((ext_vector_type(8))) short bf16x8;     // 8 bf16 = 4 VGPR
typedef __attribute__((ext_vector_type(8))) unsigned short u16x8;
typedef __attribute__((ext_vector_type(4))) float f32x4;

__device__ __forceinline__ unsigned short f2bf(float f) {
  union { float f; unsigned int u; } c; c.f = f;
  unsigned int u = c.u + 0x7fffu + ((c.u >> 16) & 1u);   // RNE
  return (unsigned short)(u >> 16);
}
__device__ __forceinline__ float bf2f(unsigned short h) {
  union { unsigned int u; float f; } c; c.u = ((unsigned int)h) << 16;
  return c.f;
}

__device__ __forceinline__ void gload16(const void* g, void* l) {
  __builtin_amdgcn_global_load_lds(
      (const __attribute__((address_space(1))) void*)g,
      (__attribute__((address_space(3))) void*)l, 16, 0, 0);
}

// ---------------------------------------------------------------------------
// RMSNorm (fp32 in)
// ---------------------------------------------------------------------------
__global__ __launch_bounds__(256)
void rmsnorm_bf16(const float* __restrict__ x, const float* __restrict__ g,
                  unsigned short* __restrict__ y)
{
  const long row = blockIdx.x;
  const float* xr = x + row * 2048;
  const int t = threadIdx.x;
  float4 a = *(const float4*)(xr + t * 8);
  float4 b = *(const float4*)(xr + t * 8 + 4);
  float ss = a.x*a.x + a.y*a.y + a.z*a.z + a.w*a.w
           + b.x*b.x + b.y*b.y + b.z*b.z + b.w*b.w;
#pragma unroll
  for (int off = 32; off >= 1; off >>= 1) ss += __shfl_xor(ss, off, 64);
  __shared__ float sm[4];
  if ((t & 63) == 0) sm[t >> 6] = ss;
  __syncthreads();
  float inv = rsqrtf((sm[0] + sm[1] + sm[2] + sm[3]) * (1.0f / 2048.0f) + 1e-6f);
  float4 ga = *(const float4*)(g + t * 8);
  float4 gb = *(const float4*)(g + t * 8 + 4);
  u16x8 ov;
  ov[0] = f2bf(a.x * inv * ga.x); ov[1] = f2bf(a.y * inv * ga.y);
  ov[2] = f2bf(a.z * inv * ga.z); ov[3] = f2bf(a.w * inv * ga.w);
  ov[4] = f2bf(b.x * inv * gb.x); ov[5] = f2bf(b.y * inv * gb.y);
  ov[6] = f2bf(b.z * inv * gb.z); ov[7] = f2bf(b.w * inv * gb.w);
  *(u16x8*)(y + row * 2048 + t * 8) = ov;
}

// ---------------------------------------------------------------------------
// RMSNorm (bf16 in)
// ---------------------------------------------------------------------------
__global__ __launch_bounds__(256)
void rmsnorm_bf16_in(const unsigned short* __restrict__ x, const float* __restrict__ g,
                     unsigned short* __restrict__ y)
{
  const long row = blockIdx.x;
  const unsigned short* xr = x + row * 2048;
  const int t = threadIdx.x;
  u16x8 iv = *(const u16x8*)(xr + t * 8);
  float v[8];
  float ss = 0.f;
#pragma unroll
  for (int j = 0; j < 8; j++) { v[j] = bf2f(iv[j]); ss += v[j] * v[j]; }
#pragma unroll
  for (int off = 32; off >= 1; off >>= 1) ss += __shfl_xor(ss, off, 64);
  __shared__ float sm[4];
  if ((t & 63) == 0) sm[t >> 6] = ss;
  __syncthreads();
  float inv = rsqrtf((sm[0] + sm[1] + sm[2] + sm[3]) * (1.0f / 2048.0f) + 1e-6f);
  float4 ga = *(const float4*)(g + t * 8);
  float4 gb = *(const float4*)(g + t * 8 + 4);
  u16x8 ov;
  ov[0] = f2bf(v[0] * inv * ga.x); ov[1] = f2bf(v[1] * inv * ga.y);
  ov[2] = f2bf(v[2] * inv * ga.z); ov[3] = f2bf(v[3] * inv * ga.w);
  ov[4] = f2bf(v[4] * inv * gb.x); ov[5] = f2bf(v[5] * inv * gb.y);
  ov[6] = f2bf(v[6] * inv * gb.z); ov[7] = f2bf(v[7] * inv * gb.w);
  *(u16x8*)(y + row * 2048 + t * 8) = ov;
}

// ---------------------------------------------------------------------------
// Weight transpose + fp32->bf16 (64x64 tile, u16x8 stores)
// ---------------------------------------------------------------------------
__global__ __launch_bounds__(256)
void transpose_w(const float* __restrict__ in, unsigned short* __restrict__ outp,
                 int K, int N)
{
  __shared__ unsigned short tile[64 * 64];
  const int n0 = blockIdx.x * 64, k0 = blockIdx.y * 64;
  const int tid = threadIdx.x;
#pragma unroll
  for (int p = 0; p < 4; p++) {
    int f = tid + p * 256;
    int row = f >> 4, c4 = f & 15;
    float4 v = *(const float4*)(in + (long)(k0 + row) * N + n0 + c4 * 4);
    ushort4 o;
    o.x = f2bf(v.x); o.y = f2bf(v.y); o.z = f2bf(v.z); o.w = f2bf(v.w);
    *(ushort4*)((char*)tile + row * 128
                + (((c4 >> 1) ^ (row >> 3)) * 16) + (c4 & 1) * 8) = o;
  }
  __syncthreads();
#pragma unroll
  for (int q = 0; q < 2; q++) {
    int idx = tid + q * 256;
    int nl = idx >> 3, l8 = idx & 7;
    u16x8 o;
#pragma unroll
    for (int j = 0; j < 8; j++) {
      int kl = l8 * 8 + j;
      o[j] = *(const unsigned short*)((char*)tile + kl * 128
               + (((nl >> 3) ^ (kl >> 3)) * 16) + (nl & 7) * 2);
    }
    *(u16x8*)(outp + (long)(n0 + nl) * K + k0 + l8 * 8) = o;
  }
}

// ---------------------------------------------------------------------------
// gemm256: 256x256 tile, BK=64, 8 waves (2M x 4N), 8-phase counted-vmcnt
// schedule. LDS 128KB = 2buf x {A,B} x 2 M-halves x [128 rows][64 k] bf16.
// Region(buf,mat,half) = buf*65536 + mat*32768 + half*16384 bytes.
// Stage schedule/iter (2 K-tiles): ph0 A10<-t1, ph1 A11<-t1, ph2 B00<-t2,
// ph3 B01<-t2 +vm4, ph4 A00<-t2, ph5 A01<-t2, ph6 B10<-t3, ph7 B11<-t3 +vm4.
// EPI: 0=bf16 (+vT transpose for qkv V-section), 1=silu->bf16, 2=mul->bf16.
// ---------------------------------------------------------------------------
#define PH_BAR __builtin_amdgcn_s_barrier()
#define SB0 __builtin_amdgcn_sched_barrier(0)
#define LGKM0 asm volatile("s_waitcnt lgkmcnt(0)" ::: "memory")
#define VM4 asm volatile("s_waitcnt vmcnt(4)" ::: "memory");
#define VM0 asm volatile("s_waitcnt vmcnt(0)" ::: "memory");

#define STGA(RBASE, h, t) { \
  gload16(Asb + (long)((h) * 128) * K + (t) * 64, L + (RBASE) + wave * 1024); \
  gload16(Asb + (long)((h) * 128 + 64) * K + (t) * 64, L + (RBASE) + 8192 + wave * 1024); }
#define STGB(RBASE, h, t) { \
  gload16(Bsb + (long)((h) * 128) * K + (t) * 64, L + (RBASE) + wave * 1024); \
  gload16(Bsb + (long)((h) * 128 + 64) * K + (t) * 64, L + (RBASE) + 8192 + wave * 1024); }

#define LDB8(RBASE) { \
  bfr0[0] = *(const bf16x8*)(L + (RBASE) + bbase + 0 * 2048 + k0off); \
  bfr1[0] = *(const bf16x8*)(L + (RBASE) + bbase + 0 * 2048 + k1off); \
  bfr0[1] = *(const bf16x8*)(L + (RBASE) + bbase + 1 * 2048 + k0off); \
  bfr1[1] = *(const bf16x8*)(L + (RBASE) + bbase + 1 * 2048 + k1off); \
  bfr0[2] = *(const bf16x8*)(L + (RBASE) + bbase + 2 * 2048 + k0off); \
  bfr1[2] = *(const bf16x8*)(L + (RBASE) + bbase + 2 * 2048 + k1off); \
  bfr0[3] = *(const bf16x8*)(L + (RBASE) + bbase + 3 * 2048 + k0off); \
  bfr1[3] = *(const bf16x8*)(L + (RBASE) + bbase + 3 * 2048 + k1off); }

#define NOP_

#define PHASE(RAc, mg, PRE, STGOP, GATE) { \
  bf16x8 a00, a01, a10, a11; \
  a00 = *(const bf16x8*)(L + (RAc) + abase + (mg) * 2048 + k0off); \
  a01 = *(const bf16x8*)(L + (RAc) + abase + (mg) * 2048 + k1off); \
  a10 = *(const bf16x8*)(L + (RAc) + abase + ((mg) + 1) * 2048 + k0off); \
  a11 = *(const bf16x8*)(L + (RAc) + abase + ((mg) + 1) * 2048 + k1off); \
  PRE STGOP \
  SB0; PH_BAR; LGKM0; SB0; \
  __builtin_amdgcn_s_setprio(1); \
  _Pragma("unroll") \
  for (int n = 0; n < 4; n++) { \
    acc[(mg)][n]     = __builtin_amdgcn_mfma_f32_16x16x32_bf16(a00, bfr0[n], acc[(mg)][n], 0, 0, 0); \
    acc[(mg)][n]     = __builtin_amdgcn_mfma_f32_16x16x32_bf16(a01, bfr1[n], acc[(mg)][n], 0, 0, 0); \
    acc[(mg) + 1][n] = __builtin_amdgcn_mfma_f32_16x16x32_bf16(a10, bfr0[n], acc[(mg) + 1][n], 0, 0, 0); \
    acc[(mg) + 1][n] = __builtin_amdgcn_mfma_f32_16x16x32_bf16(a11, bfr1[n], acc[(mg) + 1][n], 0, 0, 0); } \
  __builtin_amdgcn_s_setprio(0); SB0; \
  GATE PH_BAR; SB0; }

template<int EPI>
__global__ __launch_bounds__(512, 1)
void gemm256(const unsigned short* __restrict__ A,
             const unsigned short* __restrict__ Bt,
             void* __restrict__ Cout,
             const unsigned short* __restrict__ mulsrc,
             unsigned short* __restrict__ vTout,
             int M, int N, int K)
{
  __shared__ alignas(16) char L[131072];
  const int tid = threadIdx.x;
  const int lane = tid & 63, wave = tid >> 6;
  const int wr = wave >> 2, wc = wave & 3;
  const int l15 = lane & 15, lg = lane >> 4;

  const int nwg = gridDim.x * gridDim.y;
  int wg = blockIdx.y * gridDim.x + blockIdx.x;
  wg = (wg & 7) * (nwg >> 3) + (wg >> 3);
  const int bx = wg % gridDim.x, by = wg / gridDim.x;
  const long m0 = (long)by * 256, n0 = (long)bx * 256;

  f32x4 acc[8][4];
#pragma unroll
  for (int m = 0; m < 8; m++)
#pragma unroll
    for (int n = 0; n < 4; n++) acc[m][n] = f32x4{0.f, 0.f, 0.f, 0.f};

  // staging thread geometry: rows r0/r0+64 of a [128][64] region, chunk c0
  const int r0 = tid >> 3, c0 = tid & 7;
  const int csw = c0 ^ (r0 & 7);        // pre-swizzled source chunk (involution)
  const unsigned short* Asb = A + (m0 + r0) * (long)K + csw * 8;
  const unsigned short* Bsb = Bt + (n0 + r0) * (long)K + csw * 8;

  // fragment ds_read offsets (bytes within region)
  const int x = (l15 & 7) << 4;
  const int k0off = (lg * 16) ^ x;
  const int k1off = (64 + lg * 16) ^ x;
  const int abase = l15 * 128;                      // + m*2048
  const int bbase = ((wc & 1) * 64 + l15) * 128;    // + n*2048

  // region bases for reads
  const int RA_r0 = wr * 16384;
  const int RB_r0 = 32768 + (wc >> 1) * 16384;
  const int RA_r1 = 65536 + RA_r0;
  const int RB_r1 = 65536 + RB_r0;

  bf16x8 bfr0[4], bfr1[4];

  const int nkt = K >> 6, nit = nkt >> 1;

  // prologue: T0 fully (A00,A01,B00,B01) + T1's B halves; gate first 4 stages
  STGA(0, 0, 0) STGA(16384, 1, 0)
  STGB(32768, 0, 0) STGB(32768 + 16384, 1, 0)
  STGB(65536 + 32768, 0, 1) STGB(65536 + 32768 + 16384, 1, 1)
  VM4 PH_BAR; SB0;

  for (int it = 0; it < nit - 1; ++it) {
    const int t1 = 2 * it + 1, t2 = t1 + 1, t3 = t1 + 2;
    PHASE(RA_r0, 0, LDB8(RB_r0), STGA(65536, 0, t1), NOP_)
    PHASE(RA_r0, 2, NOP_, STGA(65536 + 16384, 1, t1), NOP_)
    PHASE(RA_r0, 4, NOP_, STGB(32768, 0, t2), NOP_)
    PHASE(RA_r0, 6, NOP_, STGB(32768 + 16384, 1, t2), VM4)
    PHASE(RA_r1, 0, LDB8(RB_r1), STGA(0, 0, t2), NOP_)
    PHASE(RA_r1, 2, NOP_, STGA(16384, 1, t2), NOP_)
    PHASE(RA_r1, 4, NOP_, STGB(65536 + 32768, 0, t3), NOP_)
    PHASE(RA_r1, 6, NOP_, STGB(65536 + 32768 + 16384, 1, t3), VM4)
  }
  { // drain: tiles nkt-2 (buf0), nkt-1 (buf1); only A1 halves left to stage
    const int t1 = nkt - 1;
    PHASE(RA_r0, 0, LDB8(RB_r0), STGA(65536, 0, t1), NOP_)
    PHASE(RA_r0, 2, NOP_, STGA(65536 + 16384, 1, t1), NOP_)
    PHASE(RA_r0, 4, NOP_, NOP_, NOP_)
    PHASE(RA_r0, 6, NOP_, NOP_, VM0)
    PHASE(RA_r1, 0, LDB8(RB_r1), NOP_, NOP_)
    PHASE(RA_r1, 2, NOP_, NOP_, NOP_)
    PHASE(RA_r1, 4, NOP_, NOP_, NOP_)
    PHASE(RA_r1, 6, NOP_, NOP_, NOP_)
  }

  // epilogue: stage 256x256 bf16 C tile in L (chunk-swizzled), coalesced out
  __syncthreads();
  unsigned short* Cl = (unsigned short*)L;   // [256 rows][32 chunks of 8]
#pragma unroll
  for (int m = 0; m < 8; m++)
#pragma unroll
    for (int n = 0; n < 4; n++)
#pragma unroll
      for (int r = 0; r < 4; r++) {
        float v = acc[m][n][r];
        if (EPI == 1) v = v / (1.f + __expf(-v));
        int row = wr * 128 + m * 16 + lg * 4 + r;
        int col = wc * 64 + n * 16 + l15;
        Cl[row * 256 + (((col >> 3) ^ (row >> 3)) & 31) * 8 + (col & 7)] = f2bf(v);
      }
  __syncthreads();
#pragma unroll
  for (int rnd = 0; rnd < 16; rnd++) {
    int id = tid + rnd * 512;
    int row = id >> 5, c = (id & 31) * 8;
    int ch = (id & 31) ^ ((row >> 3) & 31);
    long grow = m0 + row, gcol = n0 + c;
    u16x8 v = *(const u16x8*)(Cl + row * 256 + ch * 8);
    if (EPI == 2) {
      u16x8 mm = *(const u16x8*)(mulsrc + grow * N + gcol);
#pragma unroll
      for (int j = 0; j < 8; j++) v[j] = f2bf(bf2f(v[j]) * bf2f(mm[j]));
    }
    *(u16x8*)((unsigned short*)Cout + grow * N + gcol) = v;
  }

  // fused V-transpose for the qkv GEMM (tile spans 2 heads)
  if (EPI == 0 && vTout != nullptr && n0 >= 4096) {
    const int hbase = (int)((n0 - 4096) >> 7);
    const int b = (int)(m0 >> 11);
    const long s0 = m0 & 2047;
#pragma unroll
    for (int rnd = 0; rnd < 16; rnd++) {
      int id = tid + rnd * 512;
      int col = id >> 5, sc8 = (id & 31) * 8;
      int ch = ((col >> 3) ^ (id & 31)) & 31;
      u16x8 v;
#pragma unroll
      for (int j = 0; j < 8; j++)
        v[j] = Cl[(sc8 + j) * 256 + ch * 8 + (col & 7)];
      int head = col >> 7, d = col & 127;
      unsigned short* vtb = vTout + ((long)((b * 16 + hbase + head) * 128 + d)) * 2048;
      *(u16x8*)(vtb + s0 + sc8) = v;
    }
  }
}

// ---------------------------------------------------------------------------
// gemm_mt64: 64M x 128N tile for N=2048 GEMMs (1024 blocks = 4/CU, 24KB LDS).
// EPI: 4 = bf16 out with fp32 residual; 5 = fp32 out with bf16 residual.
// ---------------------------------------------------------------------------
template<int EPI>
__global__ __launch_bounds__(256)
void gemm_mt64(const unsigned short* __restrict__ A,
               const unsigned short* __restrict__ Bt,
               void* __restrict__ Cout,
               const float* __restrict__ res,
               const unsigned short* __restrict__ res16,
               int M, int N, int K)
{
  __shared__ unsigned short lds[64 * 64 + 128 * 64];
  const int tid = threadIdx.x;
  const int lane = tid & 63, wave = tid >> 6;
  const int wr = wave >> 1, wc = wave & 1;
  const int l15 = lane & 15, lg = lane >> 4;

  const int nwg = gridDim.x * gridDim.y;
  int wg = blockIdx.y * gridDim.x + blockIdx.x;
  wg = (wg & 7) * (nwg >> 3) + (wg >> 3);
  const int bx = wg % gridDim.x, by = wg / gridDim.x;
  const long m0 = (long)by * 64, n0 = (long)bx * 128;

  f32x4 acc[2][4];
#pragma unroll
  for (int m = 0; m < 2; m++)
#pragma unroll
    for (int n = 0; n < 4; n++) acc[m][n] = f32x4{0.f, 0.f, 0.f, 0.f};

  const int rsub = lane >> 3;
  const int csw = (lane & 7) ^ rsub;
  const unsigned short* Ab = A + (m0 + wave * 16 + rsub) * (long)K + csw * 8;
  const unsigned short* Bb = Bt + (n0 + wave * 32 + rsub) * (long)K + csw * 8;
  unsigned short* Al = lds + wave * 1024;
  unsigned short* Bl = lds + 4096 + wave * 2048;

  for (int kt = 0; kt < K; kt += 64) {
    __syncthreads();
#pragma unroll
    for (int i = 0; i < 2; i++)
      gload16(Ab + (long)(i * 8) * K + kt, Al + i * 512);
#pragma unroll
    for (int i = 0; i < 4; i++)
      gload16(Bb + (long)(i * 8) * K + kt, Bl + i * 512);
    __syncthreads();
#pragma unroll
    for (int kc = 0; kc < 2; kc++) {
      bf16x8 af[2], bfr[4];
#pragma unroll
      for (int m = 0; m < 2; m++) {
        int row = wr * 32 + m * 16 + l15;
        int off = row * 128 + ((kc * 64 + lg * 16) ^ ((row & 7) << 4));
        af[m] = *(const bf16x8*)((const char*)lds + off);
      }
#pragma unroll
      for (int n = 0; n < 4; n++) {
        int row = wc * 64 + n * 16 + l15;
        int off = 8192 + row * 128 + ((kc * 64 + lg * 16) ^ ((row & 7) << 4));
        bfr[n] = *(const bf16x8*)((const char*)lds + off);
      }
#pragma unroll
      for (int m = 0; m < 2; m++)
#pragma unroll
        for (int n = 0; n < 4; n++)
          acc[m][n] = __builtin_amdgcn_mfma_f32_16x16x32_bf16(af[m], bfr[n], acc[m][n], 0, 0, 0);
    }
  }

  if (EPI == 5) {
#pragma unroll
    for (int m = 0; m < 2; m++)
#pragma unroll
      for (int n = 0; n < 4; n++)
#pragma unroll
        for (int r = 0; r < 4; r++) {
          long row = m0 + wr * 32 + m * 16 + lg * 4 + r;
          long col = n0 + wc * 64 + n * 16 + l15;
          ((float*)Cout)[row * N + col] = acc[m][n][r] + bf2f(res16[row * N + col]);
        }
    return;
  }

  __syncthreads();
  unsigned short* Cl = lds;
#pragma unroll
  for (int m = 0; m < 2; m++)
#pragma unroll
    for (int n = 0; n < 4; n++)
#pragma unroll
      for (int r = 0; r < 4; r++) {
        int row = wr * 32 + m * 16 + lg * 4 + r;
        int col = wc * 64 + n * 16 + l15;
        float v = acc[m][n][r] + res[(m0 + row) * N + n0 + col];
        Cl[row * 128 + (((col >> 3) ^ (row >> 3)) & 15) * 8 + (col & 7)] = f2bf(v);
      }
  __syncthreads();
#pragma unroll
  for (int rnd = 0; rnd < 4; rnd++) {
    int id = tid + rnd * 256;
    int row = id >> 4, c = (id & 15) * 8;
    int ch = (id & 15) ^ (row >> 3);
    u16x8 v = *(const u16x8*)(Cl + row * 128 + ch * 8);
    *(u16x8*)((unsigned short*)Cout + (m0 + row) * N + n0 + c) = v;
  }
}

// ---------------------------------------------------------------------------
// Causal flash attention, paired q-tiles (R3-proven QSTEP).
// ---------------------------------------------------------------------------
#define QSTEP(qf, mrow, lrow, o, qb, isdiag) do {                              \
    f32x4 sacc[4];                                                             \
    __builtin_amdgcn_s_setprio(1);                                             \
    _Pragma("unroll")                                                          \
    for (int cg = 0; cg < 4; cg++) {                                           \
      f32x4 a = f32x4{0.f, 0.f, 0.f, 0.f};                                     \
      _Pragma("unroll")                                                        \
      for (int kc = 0; kc < 4; kc++) {                                         \
        int krow = cg * 16 + l15;                                              \
        bf16x8 kf = *(const bf16x8*)((char*)Klds +                             \
            (krow * 256 + ((kc * 64 + lg * 16) ^ ((krow & 7) << 4))));         \
        a = __builtin_amdgcn_mfma_f32_16x16x32_bf16(qf[kc], kf, a, 0, 0, 0);   \
      }                                                                        \
      sacc[cg] = a;                                                            \
    }                                                                          \
    __builtin_amdgcn_s_setprio(0);                                             \
    float p[4][4], pm[4];                                                      \
    _Pragma("unroll")                                                          \
    for (int r = 0; r < 4; r++) pm[r] = -1e30f;                                \
    _Pragma("unroll")                                                          \
    for (int cg = 0; cg < 4; cg++)                                             \
      _Pragma("unroll")                                                        \
      for (int r = 0; r < 4; r++) {                                            \
        float v = sacc[cg][r] * scale;                                         \
        if (isdiag) {                                                          \
          int kvg = kv0 + cg * 16 + l15;                                       \
          int qg = qb + w * 16 + lg * 4 + r;                                   \
          if (kvg > qg) v = -1e30f;                                            \
        }                                                                      \
        p[cg][r] = v;                                                          \
        pm[r] = fmaxf(pm[r], v);                                               \
      }                                                                        \
    _Pragma("unroll")                                                          \
    for (int r = 0; r < 4; r++) {                                              \
      _Pragma("unroll")                                                        \
      for (int off = 1; off < 16; off <<= 1)                                   \
        pm[r] = fmaxf(pm[r], __shfl_xor(pm[r], off, 64));                      \
      float mn = fmaxf(mrow[r], pm[r]);                                        \
      float al = __expf(mrow[r] - mn);                                         \
      mrow[r] = mn;                                                            \
      float s = 0.f;                                                           \
      _Pragma("unroll")                                                        \
      for (int cg = 0; cg < 4; cg++) { p[cg][r] = __expf(p[cg][r] - mn); s += p[cg][r]; } \
      _Pragma("unroll")                                                        \
      for (int off = 1; off < 16; off <<= 1)                                   \
        s += __shfl_xor(s, off, 64);                                           \
      lrow[r] = lrow[r] * al + s;                                              \
      _Pragma("unroll")                                                        \
      for (int dg = 0; dg < 8; dg++) o[dg][r] *= al;                           \
    }                                                                          \
    _Pragma("unroll")                                                          \
    for (int cg = 0; cg < 4; cg++)                                             \
      _Pragma("unroll")                                                        \
      for (int r = 0; r < 4; r++) {                                            \
        int q = lg * 4 + r;                                                    \
        *((unsigned short*)((char*)&Plds[w][0] +                               \
            (q * 128 + (((cg * 16 + l15) * 2) ^ ((q & 7) << 4))))) = f2bf(p[cg][r]); \
      }                                                                        \
    asm volatile("s_waitcnt lgkmcnt(0)" ::: "memory");                         \
    __builtin_amdgcn_sched_barrier(0);                                         \
    __builtin_amdgcn_s_setprio(1);                                             \
    _Pragma("unroll")                                                          \
    for (int kc = 0; kc < 2; kc++) {                                           \
      bf16x8 pa = *(const bf16x8*)((char*)&Plds[w][0] +                        \
          (l15 * 128 + ((kc * 64 + lg * 16) ^ ((l15 & 7) << 4))));             \
      _Pragma("unroll")                                                        \
      for (int dg = 0; dg < 8; dg++) {                                         \
        int d = dg * 16 + l15;                                                 \
        bf16x8 vf = *(const bf16x8*)((char*)Vlds +                             \
            (d * 128 + ((kc * 64 + lg * 16) ^ ((d & 7) << 4))));               \
        o[dg] = __builtin_amdgcn_mfma_f32_16x16x32_bf16(pa, vf, o[dg], 0, 0, 0); \
      }                                                                        \
    }                                                                          \
    __builtin_amdgcn_s_setprio(0);                                             \
  } while (0)

__global__ __launch_bounds__(256, 2)
void attn_fwd(const unsigned short* __restrict__ qkv,
              const unsigned short* __restrict__ vT,
              unsigned short* __restrict__ out)
{
  __shared__ unsigned short Klds[64 * 128];
  __shared__ unsigned short Vlds[128 * 64];
  __shared__ unsigned short Plds[4][16 * 64];
  const int tid = threadIdx.x, lane = tid & 63, w = tid >> 6;
  const int l15 = lane & 15, lg = lane >> 4;

  const int nwg = gridDim.x * gridDim.y;
  int wg = blockIdx.y * gridDim.x + blockIdx.x;
  wg = (wg & 7) * (nwg >> 3) + (wg >> 3);
  const int ip = wg % 16;
  const int bh = wg / 16;
  const int b = bh >> 4, hh = bh & 15;

  const int qbA = ip * 64, qbB = (31 - ip) * 64;
  const long base = (long)b * 2048 * 6144;
  const int qoff = hh * 128, koff = 2048 + hh * 128;
  const unsigned short* vTg = vT + (long)bh * (128 * 2048);

  bf16x8 qfA[4], qfB[4];
  {
    long qrA = qbA + w * 16 + l15, qrB = qbB + w * 16 + l15;
#pragma unroll
    for (int kc = 0; kc < 4; kc++) {
      qfA[kc] = *(const bf16x8*)(qkv + base + qrA * 6144 + qoff + kc * 32 + lg * 8);
      qfB[kc] = *(const bf16x8*)(qkv + base + qrB * 6144 + qoff + kc * 32 + lg * 8);
    }
  }
  f32x4 oA[8], oB[8];
#pragma unroll
  for (int dg = 0; dg < 8; dg++) {
    oA[dg] = f32x4{0.f, 0.f, 0.f, 0.f};
    oB[dg] = f32x4{0.f, 0.f, 0.f, 0.f};
  }
  float mA[4] = {-1e30f, -1e30f, -1e30f, -1e30f}, lA[4] = {0.f, 0.f, 0.f, 0.f};
  float mB[4] = {-1e30f, -1e30f, -1e30f, -1e30f}, lB[4] = {0.f, 0.f, 0.f, 0.f};
  const float scale = 0.08838834764831845f;

  const int s_st = tid >> 4, d0 = (tid & 15) * 8;
  const int vrow = tid >> 3, vc = tid & 7;

  const int nt = 32 - ip;
  for (int t = 0; t < nt; t++) {
    const int kv0 = t * 64;
#pragma unroll
    for (int u = 0; u < 4; u++) {
      int srow = s_st + u * 16;
      uint4 kk = *(const uint4*)(qkv + base + (long)(kv0 + srow) * 6144 + koff + d0);
      *(uint4*)((char*)Klds + (srow * 256 + ((d0 * 2) ^ ((srow & 7) << 4)))) = kk;
    }
#pragma unroll
    for (int u = 0; u < 4; u++) {
      int d = vrow + u * 32;
      uint4 vv = *(const uint4*)(vTg + (long)d * 2048 + kv0 + vc * 8);
      *(uint4*)((char*)Vlds + (d * 128 + ((vc * 16) ^ ((d & 7) << 4)))) = vv;
    }
    __syncthreads();

    if (t <= ip) QSTEP(qfA, mA, lA, oA, qbA, (t == ip));
    QSTEP(qfB, mB, lB, oB, qbB, (t == nt - 1));

    __syncthreads();
  }

#pragma unroll
  for (int r = 0; r < 4; r++) {
    float invA = 1.f / lA[r], invB = 1.f / lB[r];
    long rowA = (long)b * 2048 + qbA + w * 16 + lg * 4 + r;
    long rowB = (long)b * 2048 + qbB + w * 16 + lg * 4 + r;
#pragma unroll
    for (int dg = 0; dg < 8; dg++) {
      out[rowA * 2048 + hh * 128 + dg * 16 + l15] = f2bf(oA[dg][r] * invA);
      out[rowB * 2048 + hh * 128 + dg * 16 + l15] = f2bf(oB[dg][r] * invB);
    }
  }
}

// ---------------------------------------------------------------------------
extern "C" void kernel_launch(void* const* d_in, const int* in_sizes, int n_in,
                              void* d_out, int out_size, void* d_ws, size_t ws_size,
                              hipStream_t stream)
{
  const float* x     = (const float*)d_in[0];
  const float* w_qkv = (const float*)d_in[1];
  const float* w_out = (const float*)d_in[2];
  const float* g1    = (const float*)d_in[3];
  const float* g2    = (const float*)d_in[4];
  const float* w1    = (const float*)d_in[5];
  const float* w3    = (const float*)d_in[6];
  const float* w2    = (const float*)d_in[7];
  float* outp = (float*)d_out;
  char* ws = (char*)d_ws;

  unsigned short* wT  = (unsigned short*)(ws);                 // 25,165,824
  unsigned short* y   = (unsigned short*)(ws + 25165824);      // 16,777,216
  unsigned short* qkv = (unsigned short*)(ws + 41943040);      // 50,331,648
  unsigned short* att = (unsigned short*)(ws + 92274688);      // 16,777,216
  unsigned short* x1b = (unsigned short*)(ws + 109051904);     // 16,777,216 (bf16 residual)
  unsigned short* s1  = (unsigned short*)(ws + 142606336);     // 46,137,344
  unsigned short* vTb = s1;                                    // vT (16.8MB), dead before s1
  unsigned short* h   = qkv;                                   // reuse (qkv dead after attn)

  // x1b = bf16(x + attn(rmsnorm(x,g1)) @ w_out)
  rmsnorm_bf16<<<4096, 256, 0, stream>>>(x, g1, y);
  transpose_w<<<dim3(96, 32), 256, 0, stream>>>(w_qkv, wT, 2048, 6144);
  gemm256<0><<<dim3(24, 16), 512, 0, stream>>>(y, wT, qkv, nullptr, vTb, 4096, 6144, 2048);
  attn_fwd<<<dim3(16, 32), 256, 0, stream>>>(qkv, vTb, att);
  transpose_w<<<dim3(32, 32), 256, 0, stream>>>(w_out, wT, 2048, 2048);
  gemm_mt64<4><<<dim3(16, 64), 256, 0, stream>>>(att, wT, x1b, x, nullptr, 4096, 2048, 2048);

  // out = x1 + swiglu(rmsnorm(x1,g2))
  rmsnorm_bf16_in<<<4096, 256, 0, stream>>>(x1b, g2, y);
  transpose_w<<<dim3(88, 32), 256, 0, stream>>>(w1, wT, 2048, 5632);
  gemm256<1><<<dim3(22, 16), 512, 0, stream>>>(y, wT, s1, nullptr, nullptr, 4096, 5632, 2048);
  transpose_w<<<dim3(88, 32), 256, 0, stream>>>(w3, wT, 2048, 5632);
  gemm256<2><<<dim3(22, 16), 512, 0, stream>>>(y, wT, h, s1, nullptr, 4096, 5632, 2048);
  transpose_w<<<dim3(32, 88), 256, 0, stream>>>(w2, wT, 5632, 2048);
  gemm_mt64<5><<<dim3(16, 64), 256, 0, stream>>>(h, wT, outp, nullptr, x1b, 4096, 2048, 5632);
}

// Round 14
// 701.808 us; speedup vs baseline: 1.0505x; 1.0505x over previous
//
#include <hip/hip_runtime.h>
#include <hip/hip_bf16.h>
#include <stdint.h>

// LLaMA block on MI355X. All matmuls in bf16 MFMA (16x16x32), fp32 accumulate.
// Dims fixed: B=2, S=2048, D=2048, H=16, hd=128, FF=5632.
// Structure lessons: m97 2-barrier GEMM needs >=4 blocks/CU overlap (R4-R7);
// LDS <= 32KB/block for GEMM. NEVER raise launch_bounds min-waves on a
// register-fat kernel (R9). 8-phase 256^2 schedule: CLOSED after 3 attempts
// (R4/R6/R13 all 23-24% MfmaUtil regardless of LDS geometry — 1-block/CU
// barrier-lockstep is the binding constraint, not bank conflicts).

typedef __attribute__((ext_vector_type(8))) short bf16x8;     // 8 bf16 = 4 VGPR
typedef __attribute__((ext_vector_type(8))) unsigned short u16x8;
typedef __attribute__((ext_vector_type(4))) float f32x4;

__device__ __forceinline__ unsigned short f2bf(float f) {
  union { float f; unsigned int u; } c; c.f = f;
  unsigned int u = c.u + 0x7fffu + ((c.u >> 16) & 1u);   // RNE
  return (unsigned short)(u >> 16);
}
__device__ __forceinline__ float bf2f(unsigned short h) {
  union { unsigned int u; float f; } c; c.u = ((unsigned int)h) << 16;
  return c.f;
}

// async global->LDS, 16B per lane; LDS dest is wave-uniform base + lane*16
__device__ __forceinline__ void gload16(const void* g, void* l) {
  __builtin_amdgcn_global_load_lds(
      (const __attribute__((address_space(1))) void*)g,
      (__attribute__((address_space(3))) void*)l, 16, 0, 0);
}

// ---------------------------------------------------------------------------
// RMSNorm (fp32 in): [rows][2048] -> bf16
// ---------------------------------------------------------------------------
__global__ __launch_bounds__(256)
void rmsnorm_bf16(const float* __restrict__ x, const float* __restrict__ g,
                  unsigned short* __restrict__ y)
{
  const long row = blockIdx.x;
  const float* xr = x + row * 2048;
  const int t = threadIdx.x;
  float4 a = *(const float4*)(xr + t * 8);
  float4 b = *(const float4*)(xr + t * 8 + 4);
  float ss = a.x*a.x + a.y*a.y + a.z*a.z + a.w*a.w
           + b.x*b.x + b.y*b.y + b.z*b.z + b.w*b.w;
#pragma unroll
  for (int off = 32; off >= 1; off >>= 1) ss += __shfl_xor(ss, off, 64);
  __shared__ float sm[4];
  if ((t & 63) == 0) sm[t >> 6] = ss;
  __syncthreads();
  float inv = rsqrtf((sm[0] + sm[1] + sm[2] + sm[3]) * (1.0f / 2048.0f) + 1e-6f);
  float4 ga = *(const float4*)(g + t * 8);
  float4 gb = *(const float4*)(g + t * 8 + 4);
  u16x8 ov;
  ov[0] = f2bf(a.x * inv * ga.x); ov[1] = f2bf(a.y * inv * ga.y);
  ov[2] = f2bf(a.z * inv * ga.z); ov[3] = f2bf(a.w * inv * ga.w);
  ov[4] = f2bf(b.x * inv * gb.x); ov[5] = f2bf(b.y * inv * gb.y);
  ov[6] = f2bf(b.z * inv * gb.z); ov[7] = f2bf(b.w * inv * gb.w);
  *(u16x8*)(y + row * 2048 + t * 8) = ov;
}

// ---------------------------------------------------------------------------
// RMSNorm (bf16 in): [rows][2048] -> bf16
// ---------------------------------------------------------------------------
__global__ __launch_bounds__(256)
void rmsnorm_bf16_in(const unsigned short* __restrict__ x, const float* __restrict__ g,
                     unsigned short* __restrict__ y)
{
  const long row = blockIdx.x;
  const unsigned short* xr = x + row * 2048;
  const int t = threadIdx.x;
  u16x8 iv = *(const u16x8*)(xr + t * 8);
  float v[8];
  float ss = 0.f;
#pragma unroll
  for (int j = 0; j < 8; j++) { v[j] = bf2f(iv[j]); ss += v[j] * v[j]; }
#pragma unroll
  for (int off = 32; off >= 1; off >>= 1) ss += __shfl_xor(ss, off, 64);
  __shared__ float sm[4];
  if ((t & 63) == 0) sm[t >> 6] = ss;
  __syncthreads();
  float inv = rsqrtf((sm[0] + sm[1] + sm[2] + sm[3]) * (1.0f / 2048.0f) + 1e-6f);
  float4 ga = *(const float4*)(g + t * 8);
  float4 gb = *(const float4*)(g + t * 8 + 4);
  u16x8 ov;
  ov[0] = f2bf(v[0] * inv * ga.x); ov[1] = f2bf(v[1] * inv * ga.y);
  ov[2] = f2bf(v[2] * inv * ga.z); ov[3] = f2bf(v[3] * inv * ga.w);
  ov[4] = f2bf(v[4] * inv * gb.x); ov[5] = f2bf(v[5] * inv * gb.y);
  ov[6] = f2bf(v[6] * inv * gb.z); ov[7] = f2bf(v[7] * inv * gb.w);
  *(u16x8*)(y + row * 2048 + t * 8) = ov;
}

// ---------------------------------------------------------------------------
// Weight transpose + fp32->bf16: in [K][N] f32 -> out [N][K] bf16.
// 64x64 tile; float4 reads (256B segments), u16x8 writes (128B/out-row).
// ---------------------------------------------------------------------------
__global__ __launch_bounds__(256)
void transpose_w(const float* __restrict__ in, unsigned short* __restrict__ outp,
                 int K, int N)
{
  __shared__ unsigned short tile[64 * 64];   // swizzled, 8KB
  const int n0 = blockIdx.x * 64, k0 = blockIdx.y * 64;
  const int tid = threadIdx.x;
#pragma unroll
  for (int p = 0; p < 4; p++) {
    int f = tid + p * 256;
    int row = f >> 4, c4 = f & 15;          // k-local row, float4 column chunk
    float4 v = *(const float4*)(in + (long)(k0 + row) * N + n0 + c4 * 4);
    ushort4 o;
    o.x = f2bf(v.x); o.y = f2bf(v.y); o.z = f2bf(v.z); o.w = f2bf(v.w);
    *(ushort4*)((char*)tile + row * 128
                + (((c4 >> 1) ^ (row >> 3)) * 16) + (c4 & 1) * 8) = o;
  }
  __syncthreads();
#pragma unroll
  for (int q = 0; q < 2; q++) {
    int idx = tid + q * 256;
    int nl = idx >> 3, l8 = idx & 7;        // n-local row, 8-elem k chunk
    u16x8 o;
#pragma unroll
    for (int j = 0; j < 8; j++) {
      int kl = l8 * 8 + j;
      o[j] = *(const unsigned short*)((char*)tile + kl * 128
               + (((nl >> 3) ^ (kl >> 3)) * 16) + (nl & 7) * 2);
    }
    *(u16x8*)(outp + (long)(n0 + nl) * K + k0 + l8 * 8) = o;
  }
}

// ---------------------------------------------------------------------------
// GEMM (m97 128x128 structure, proven): C = A * Bt^T.
// EPI: 0=bf16 store, 1=silu->bf16, 2=mul(mulsrc)->bf16, 3=+res(fp32)->fp32.
// For EPI==0 with vTout != nullptr (qkv GEMM): V-section tiles (n0>=4096) are
// additionally written transposed to vT[b*16+h][d][s] (chunk-swizzled LDS).
// ---------------------------------------------------------------------------
template<int EPI>
__global__ __launch_bounds__(256)
void gemm_bt(const unsigned short* __restrict__ A,
             const unsigned short* __restrict__ Bt,
             void* __restrict__ Cout,
             const float* __restrict__ res,
             const unsigned short* __restrict__ mulsrc,
             unsigned short* __restrict__ vTout,
             int M, int N, int K)
{
  __shared__ unsigned short lds[2 * 128 * 64];
  const int tid = threadIdx.x;
  const int lane = tid & 63, wave = tid >> 6;
  const int wr = wave >> 1, wc = wave & 1;
  const int l15 = lane & 15, lg = lane >> 4;

  const int nwg = gridDim.x * gridDim.y;
  int wg = blockIdx.y * gridDim.x + blockIdx.x;
  wg = (wg & 7) * (nwg >> 3) + (wg >> 3);
  const int bx = wg % gridDim.x, by = wg / gridDim.x;
  const long m0 = (long)by * 128, n0 = (long)bx * 128;

  f32x4 acc[4][4];
#pragma unroll
  for (int m = 0; m < 4; m++)
#pragma unroll
    for (int n = 0; n < 4; n++) acc[m][n] = f32x4{0.f, 0.f, 0.f, 0.f};

  const int rsub = lane >> 3;
  const int csw = (lane & 7) ^ rsub;
  const unsigned short* Ab = A + (m0 + wave * 32 + rsub) * (long)K + csw * 8;
  const unsigned short* Bb = Bt + (n0 + wave * 32 + rsub) * (long)K + csw * 8;
  unsigned short* Al = lds + wave * 2048;
  unsigned short* Bl = lds + 8192 + wave * 2048;

  for (int kt = 0; kt < K; kt += 64) {
    __syncthreads();
#pragma unroll
    for (int i = 0; i < 4; i++) {
      gload16(Ab + (long)(i * 8) * K + kt, Al + i * 512);
      gload16(Bb + (long)(i * 8) * K + kt, Bl + i * 512);
    }
    __syncthreads();
#pragma unroll
    for (int kc = 0; kc < 2; kc++) {
      bf16x8 af[4], bfr[4];
#pragma unroll
      for (int m = 0; m < 4; m++) {
        int row = wr * 64 + m * 16 + l15;
        int off = row * 128 + ((kc * 64 + lg * 16) ^ ((row & 7) << 4));
        af[m] = *(const bf16x8*)((const char*)lds + off);
      }
#pragma unroll
      for (int n = 0; n < 4; n++) {
        int row = wc * 64 + n * 16 + l15;
        int off = 16384 + row * 128 + ((kc * 64 + lg * 16) ^ ((row & 7) << 4));
        bfr[n] = *(const bf16x8*)((const char*)lds + off);
      }
#pragma unroll
      for (int m = 0; m < 4; m++)
#pragma unroll
        for (int n = 0; n < 4; n++)
          acc[m][n] = __builtin_amdgcn_mfma_f32_16x16x32_bf16(af[m], bfr[n], acc[m][n], 0, 0, 0);
    }
  }

  if (EPI == 3) {
#pragma unroll
    for (int m = 0; m < 4; m++)
#pragma unroll
      for (int n = 0; n < 4; n++)
#pragma unroll
        for (int r = 0; r < 4; r++) {
          long row = m0 + wr * 64 + m * 16 + lg * 4 + r;
          long col = n0 + wc * 64 + n * 16 + l15;
          ((float*)Cout)[row * N + col] = acc[m][n][r] + res[row * N + col];
        }
    return;
  }

  // bf16 epilogues: stage C tile in (now dead) LDS with chunk swizzle
  __syncthreads();
  unsigned short* Cl = lds;   // [128][16 chunks of 8 u16], chunk ^= row>>3
#pragma unroll
  for (int m = 0; m < 4; m++)
#pragma unroll
    for (int n = 0; n < 4; n++)
#pragma unroll
      for (int r = 0; r < 4; r++) {
        float v = acc[m][n][r];
        if (EPI == 1) v = v / (1.f + __expf(-v));
        int row = wr * 64 + m * 16 + lg * 4 + r;
        int col = wc * 64 + n * 16 + l15;
        Cl[row * 128 + (((col >> 3) ^ (row >> 3)) & 15) * 8 + (col & 7)] = f2bf(v);
      }
  __syncthreads();
#pragma unroll
  for (int r8 = 0; r8 < 8; r8++) {
    int id = tid + r8 * 256;
    int row = id >> 4, c = (id & 15) * 8;
    int ch = (id & 15) ^ (row >> 3);
    long grow = m0 + row, gcol = n0 + c;
    u16x8 v = *(const u16x8*)(Cl + row * 128 + ch * 8);
    if (EPI == 2) {
      u16x8 mm = *(const u16x8*)(mulsrc + grow * N + gcol);
#pragma unroll
      for (int j = 0; j < 8; j++) v[j] = f2bf(bf2f(v[j]) * bf2f(mm[j]));
    }
    *(u16x8*)((unsigned short*)Cout + grow * N + gcol) = v;
  }

  // fused V-transpose for the qkv GEMM: vT[b*16+h][d][s] <- C^T tile.
  if (EPI == 0 && vTout != nullptr && n0 >= 4096) {
    const int hh = (int)((n0 - 4096) >> 7);
    const int b = (int)(m0 >> 11);
    const long s0 = m0 & 2047;
    unsigned short* vtb = vTout + ((long)(b * 16 + hh) * 128) * 2048;
#pragma unroll
    for (int r8 = 0; r8 < 8; r8++) {
      int id = tid + r8 * 256;
      int d = id >> 4, sc = (id & 15) * 8;
      int ch = ((d >> 3) ^ (id & 15)) & 15;
      u16x8 v;
#pragma unroll
      for (int j = 0; j < 8; j++) v[j] = Cl[(sc + j) * 128 + ch * 8 + (d & 7)];
      *(u16x8*)(vtb + (long)d * 2048 + s0 + sc) = v;
    }
  }
}

// ---------------------------------------------------------------------------
// gemm_mt64: 64M x 128N tile for N=2048 GEMMs (1024 blocks = 4/CU, 24KB LDS).
// EPI: 4 = bf16 out with fp32 residual; 5 = fp32 out with bf16 residual.
// ---------------------------------------------------------------------------
template<int EPI>
__global__ __launch_bounds__(256)
void gemm_mt64(const unsigned short* __restrict__ A,
               const unsigned short* __restrict__ Bt,
               void* __restrict__ Cout,
               const float* __restrict__ res,
               const unsigned short* __restrict__ res16,
               int M, int N, int K)
{
  __shared__ unsigned short lds[64 * 64 + 128 * 64];   // A 8KB | B 16KB
  const int tid = threadIdx.x;
  const int lane = tid & 63, wave = tid >> 6;
  const int wr = wave >> 1, wc = wave & 1;
  const int l15 = lane & 15, lg = lane >> 4;

  const int nwg = gridDim.x * gridDim.y;
  int wg = blockIdx.y * gridDim.x + blockIdx.x;
  wg = (wg & 7) * (nwg >> 3) + (wg >> 3);
  const int bx = wg % gridDim.x, by = wg / gridDim.x;
  const long m0 = (long)by * 64, n0 = (long)bx * 128;

  f32x4 acc[2][4];
#pragma unroll
  for (int m = 0; m < 2; m++)
#pragma unroll
    for (int n = 0; n < 4; n++) acc[m][n] = f32x4{0.f, 0.f, 0.f, 0.f};

  const int rsub = lane >> 3;
  const int csw = (lane & 7) ^ rsub;
  const unsigned short* Ab = A + (m0 + wave * 16 + rsub) * (long)K + csw * 8;
  const unsigned short* Bb = Bt + (n0 + wave * 32 + rsub) * (long)K + csw * 8;
  unsigned short* Al = lds + wave * 1024;          // 16 rows * 64 cols
  unsigned short* Bl = lds + 4096 + wave * 2048;   // 32 rows * 64 cols

  for (int kt = 0; kt < K; kt += 64) {
    __syncthreads();
#pragma unroll
    for (int i = 0; i < 2; i++)
      gload16(Ab + (long)(i * 8) * K + kt, Al + i * 512);
#pragma unroll
    for (int i = 0; i < 4; i++)
      gload16(Bb + (long)(i * 8) * K + kt, Bl + i * 512);
    __syncthreads();
#pragma unroll
    for (int kc = 0; kc < 2; kc++) {
      bf16x8 af[2], bfr[4];
#pragma unroll
      for (int m = 0; m < 2; m++) {
        int row = wr * 32 + m * 16 + l15;
        int off = row * 128 + ((kc * 64 + lg * 16) ^ ((row & 7) << 4));
        af[m] = *(const bf16x8*)((const char*)lds + off);
      }
#pragma unroll
      for (int n = 0; n < 4; n++) {
        int row = wc * 64 + n * 16 + l15;
        int off = 8192 + row * 128 + ((kc * 64 + lg * 16) ^ ((row & 7) << 4));
        bfr[n] = *(const bf16x8*)((const char*)lds + off);
      }
#pragma unroll
      for (int m = 0; m < 2; m++)
#pragma unroll
        for (int n = 0; n < 4; n++)
          acc[m][n] = __builtin_amdgcn_mfma_f32_16x16x32_bf16(af[m], bfr[n], acc[m][n], 0, 0, 0);
    }
  }

  if (EPI == 5) {   // fp32 out = acc + bf16 residual, direct 64B-segment stores
#pragma unroll
    for (int m = 0; m < 2; m++)
#pragma unroll
      for (int n = 0; n < 4; n++)
#pragma unroll
        for (int r = 0; r < 4; r++) {
          long row = m0 + wr * 32 + m * 16 + lg * 4 + r;
          long col = n0 + wc * 64 + n * 16 + l15;
          ((float*)Cout)[row * N + col] = acc[m][n][r] + bf2f(res16[row * N + col]);
        }
    return;
  }

  // EPI == 4: bf16 out = acc + fp32 residual, LDS-staged coalesced stores
  __syncthreads();
  unsigned short* Cl = lds;   // [64][16 chunks of 8 u16], chunk ^= row>>3
#pragma unroll
  for (int m = 0; m < 2; m++)
#pragma unroll
    for (int n = 0; n < 4; n++)
#pragma unroll
      for (int r = 0; r < 4; r++) {
        int row = wr * 32 + m * 16 + lg * 4 + r;
        int col = wc * 64 + n * 16 + l15;
        float v = acc[m][n][r] + res[(m0 + row) * N + n0 + col];
        Cl[row * 128 + (((col >> 3) ^ (row >> 3)) & 15) * 8 + (col & 7)] = f2bf(v);
      }
  __syncthreads();
#pragma unroll
  for (int rnd = 0; rnd < 4; rnd++) {
    int id = tid + rnd * 256;           // 0..1023
    int row = id >> 4, c = (id & 15) * 8;
    int ch = (id & 15) ^ (row >> 3);
    u16x8 v = *(const u16x8*)(Cl + row * 128 + ch * 8);
    *(u16x8*)((unsigned short*)Cout + (m0 + row) * N + n0 + c) = v;
  }
}

// ---------------------------------------------------------------------------
// Causal flash attention, paired q-tiles for load balance (R3-proven QSTEP).
// launch_bounds(256,2): VGPR 120 -> HW allows 4 blocks/CU already; do NOT
// raise the floor (R9 spill lesson).
// ---------------------------------------------------------------------------
#define QSTEP(qf, mrow, lrow, o, qb, isdiag) do {                              \
    f32x4 sacc[4];                                                             \
    __builtin_amdgcn_s_setprio(1);                                             \
    _Pragma("unroll")                                                          \
    for (int cg = 0; cg < 4; cg++) {                                           \
      f32x4 a = f32x4{0.f, 0.f, 0.f, 0.f};                                     \
      _Pragma("unroll")                                                        \
      for (int kc = 0; kc < 4; kc++) {                                         \
        int krow = cg * 16 + l15;                                              \
        bf16x8 kf = *(const bf16x8*)((char*)Klds +                             \
            (krow * 256 + ((kc * 64 + lg * 16) ^ ((krow & 7) << 4))));         \
        a = __builtin_amdgcn_mfma_f32_16x16x32_bf16(qf[kc], kf, a, 0, 0, 0);   \
      }                                                                        \
      sacc[cg] = a;                                                            \
    }                                                                          \
    __builtin_amdgcn_s_setprio(0);                                             \
    float p[4][4], pm[4];                                                      \
    _Pragma("unroll")                                                          \
    for (int r = 0; r < 4; r++) pm[r] = -1e30f;                                \
    _Pragma("unroll")                                                          \
    for (int cg = 0; cg < 4; cg++)                                             \
      _Pragma("unroll")                                                        \
      for (int r = 0; r < 4; r++) {                                            \
        float v = sacc[cg][r] * scale;                                         \
        if (isdiag) {                                                          \
          int kvg = kv0 + cg * 16 + l15;                                       \
          int qg = qb + w * 16 + lg * 4 + r;                                   \
          if (kvg > qg) v = -1e30f;                                            \
        }                                                                      \
        p[cg][r] = v;                                                          \
        pm[r] = fmaxf(pm[r], v);                                               \
      }                                                                        \
    _Pragma("unroll")                                                          \
    for (int r = 0; r < 4; r++) {                                              \
      _Pragma("unroll")                                                        \
      for (int off = 1; off < 16; off <<= 1)                                   \
        pm[r] = fmaxf(pm[r], __shfl_xor(pm[r], off, 64));                      \
      float mn = fmaxf(mrow[r], pm[r]);                                        \
      float al = __expf(mrow[r] - mn);                                         \
      mrow[r] = mn;                                                            \
      float s = 0.f;                                                           \
      _Pragma("unroll")                                                        \
      for (int cg = 0; cg < 4; cg++) { p[cg][r] = __expf(p[cg][r] - mn); s += p[cg][r]; } \
      _Pragma("unroll")                                                        \
      for (int off = 1; off < 16; off <<= 1)                                   \
        s += __shfl_xor(s, off, 64);                                           \
      lrow[r] = lrow[r] * al + s;                                              \
      _Pragma("unroll")                                                        \
      for (int dg = 0; dg < 8; dg++) o[dg][r] *= al;                           \
    }                                                                          \
    _Pragma("unroll")                                                          \
    for (int cg = 0; cg < 4; cg++)                                             \
      _Pragma("unroll")                                                        \
      for (int r = 0; r < 4; r++) {                                            \
        int q = lg * 4 + r;                                                    \
        *((unsigned short*)((char*)&Plds[w][0] +                               \
            (q * 128 + (((cg * 16 + l15) * 2) ^ ((q & 7) << 4))))) = f2bf(p[cg][r]); \
      }                                                                        \
    asm volatile("s_waitcnt lgkmcnt(0)" ::: "memory");                         \
    __builtin_amdgcn_sched_barrier(0);                                         \
    __builtin_amdgcn_s_setprio(1);                                             \
    _Pragma("unroll")                                                          \
    for (int kc = 0; kc < 2; kc++) {                                           \
      bf16x8 pa = *(const bf16x8*)((char*)&Plds[w][0] +                        \
          (l15 * 128 + ((kc * 64 + lg * 16) ^ ((l15 & 7) << 4))));             \
      _Pragma("unroll")                                                        \
      for (int dg = 0; dg < 8; dg++) {                                         \
        int d = dg * 16 + l15;                                                 \
        bf16x8 vf = *(const bf16x8*)((char*)Vlds +                             \
            (d * 128 + ((kc * 64 + lg * 16) ^ ((d & 7) << 4))));               \
        o[dg] = __builtin_amdgcn_mfma_f32_16x16x32_bf16(pa, vf, o[dg], 0, 0, 0); \
      }                                                                        \
    }                                                                          \
    __builtin_amdgcn_s_setprio(0);                                             \
  } while (0)

__global__ __launch_bounds__(256, 2)
void attn_fwd(const unsigned short* __restrict__ qkv,
              const unsigned short* __restrict__ vT,
              unsigned short* __restrict__ out)
{
  __shared__ unsigned short Klds[64 * 128];   // [kv][d], XOR (kv&7)<<4
  __shared__ unsigned short Vlds[128 * 64];   // [d][kv], XOR (d&7)<<4
  __shared__ unsigned short Plds[4][16 * 64]; // per-wave P, XOR (q&7)<<4
  const int tid = threadIdx.x, lane = tid & 63, w = tid >> 6;
  const int l15 = lane & 15, lg = lane >> 4;

  const int nwg = gridDim.x * gridDim.y;
  int wg = blockIdx.y * gridDim.x + blockIdx.x;
  wg = (wg & 7) * (nwg >> 3) + (wg >> 3);
  const int ip = wg % 16;
  const int bh = wg / 16;
  const int b = bh >> 4, hh = bh & 15;

  const int qbA = ip * 64, qbB = (31 - ip) * 64;
  const long base = (long)b * 2048 * 6144;
  const int qoff = hh * 128, koff = 2048 + hh * 128;
  const unsigned short* vTg = vT + (long)bh * (128 * 2048);

  bf16x8 qfA[4], qfB[4];
  {
    long qrA = qbA + w * 16 + l15, qrB = qbB + w * 16 + l15;
#pragma unroll
    for (int kc = 0; kc < 4; kc++) {
      qfA[kc] = *(const bf16x8*)(qkv + base + qrA * 6144 + qoff + kc * 32 + lg * 8);
      qfB[kc] = *(const bf16x8*)(qkv + base + qrB * 6144 + qoff + kc * 32 + lg * 8);
    }
  }
  f32x4 oA[8], oB[8];
#pragma unroll
  for (int dg = 0; dg < 8; dg++) {
    oA[dg] = f32x4{0.f, 0.f, 0.f, 0.f};
    oB[dg] = f32x4{0.f, 0.f, 0.f, 0.f};
  }
  float mA[4] = {-1e30f, -1e30f, -1e30f, -1e30f}, lA[4] = {0.f, 0.f, 0.f, 0.f};
  float mB[4] = {-1e30f, -1e30f, -1e30f, -1e30f}, lB[4] = {0.f, 0.f, 0.f, 0.f};
  const float scale = 0.08838834764831845f;

  const int s_st = tid >> 4, d0 = (tid & 15) * 8;
  const int vrow = tid >> 3, vc = tid & 7;

  const int nt = 32 - ip;
  for (int t = 0; t < nt; t++) {
    const int kv0 = t * 64;
#pragma unroll
    for (int u = 0; u < 4; u++) {
      int srow = s_st + u * 16;
      uint4 kk = *(const uint4*)(qkv + base + (long)(kv0 + srow) * 6144 + koff + d0);
      *(uint4*)((char*)Klds + (srow * 256 + ((d0 * 2) ^ ((srow & 7) << 4)))) = kk;
    }
#pragma unroll
    for (int u = 0; u < 4; u++) {
      int d = vrow + u * 32;
      uint4 vv = *(const uint4*)(vTg + (long)d * 2048 + kv0 + vc * 8);
      *(uint4*)((char*)Vlds + (d * 128 + ((vc * 16) ^ ((d & 7) << 4)))) = vv;
    }
    __syncthreads();

    if (t <= ip) QSTEP(qfA, mA, lA, oA, qbA, (t == ip));
    QSTEP(qfB, mB, lB, oB, qbB, (t == nt - 1));

    __syncthreads();
  }

#pragma unroll
  for (int r = 0; r < 4; r++) {
    float invA = 1.f / lA[r], invB = 1.f / lB[r];
    long rowA = (long)b * 2048 + qbA + w * 16 + lg * 4 + r;
    long rowB = (long)b * 2048 + qbB + w * 16 + lg * 4 + r;
#pragma unroll
    for (int dg = 0; dg < 8; dg++) {
      out[rowA * 2048 + hh * 128 + dg * 16 + l15] = f2bf(oA[dg][r] * invA);
      out[rowB * 2048 + hh * 128 + dg * 16 + l15] = f2bf(oB[dg][r] * invB);
    }
  }
}

// ---------------------------------------------------------------------------
extern "C" void kernel_launch(void* const* d_in, const int* in_sizes, int n_in,
                              void* d_out, int out_size, void* d_ws, size_t ws_size,
                              hipStream_t stream)
{
  const float* x     = (const float*)d_in[0];
  const float* w_qkv = (const float*)d_in[1];
  const float* w_out = (const float*)d_in[2];
  const float* g1    = (const float*)d_in[3];
  const float* g2    = (const float*)d_in[4];
  const float* w1    = (const float*)d_in[5];
  const float* w3    = (const float*)d_in[6];
  const float* w2    = (const float*)d_in[7];
  float* outp = (float*)d_out;
  char* ws = (char*)d_ws;

  unsigned short* wT  = (unsigned short*)(ws);                 // 25,165,824
  unsigned short* y   = (unsigned short*)(ws + 25165824);      // 16,777,216
  unsigned short* qkv = (unsigned short*)(ws + 41943040);      // 50,331,648
  unsigned short* att = (unsigned short*)(ws + 92274688);      // 16,777,216
  unsigned short* x1b = (unsigned short*)(ws + 109051904);     // 16,777,216 (bf16 residual stream)
  unsigned short* s1  = (unsigned short*)(ws + 142606336);     // 46,137,344
  unsigned short* vTb = s1;                                    // vT (16.8MB), dead before s1
  unsigned short* h   = qkv;                                   // reuse (qkv dead after attn)

  // x1b = bf16(x + attn(rmsnorm(x,g1)) @ w_out)
  rmsnorm_bf16<<<4096, 256, 0, stream>>>(x, g1, y);
  transpose_w<<<dim3(96, 32), 256, 0, stream>>>(w_qkv, wT, 2048, 6144);
  gemm_bt<0><<<dim3(48, 32), 256, 0, stream>>>(y, wT, qkv, nullptr, nullptr, vTb, 4096, 6144, 2048);
  attn_fwd<<<dim3(16, 32), 256, 0, stream>>>(qkv, vTb, att);
  transpose_w<<<dim3(32, 32), 256, 0, stream>>>(w_out, wT, 2048, 2048);
  gemm_mt64<4><<<dim3(16, 64), 256, 0, stream>>>(att, wT, x1b, x, nullptr, 4096, 2048, 2048);

  // out = x1 + swiglu(rmsnorm(x1,g2))
  rmsnorm_bf16_in<<<4096, 256, 0, stream>>>(x1b, g2, y);
  transpose_w<<<dim3(88, 32), 256, 0, stream>>>(w1, wT, 2048, 5632);
  gemm_bt<1><<<dim3(44, 32), 256, 0, stream>>>(y, wT, s1, nullptr, nullptr, nullptr, 4096, 5632, 2048);
  transpose_w<<<dim3(88, 32), 256, 0, stream>>>(w3, wT, 2048, 5632);
  gemm_bt<2><<<dim3(44, 32), 256, 0, stream>>>(y, wT, h, nullptr, s1, nullptr, 4096, 5632, 2048);
  transpose_w<<<dim3(32, 88), 256, 0, stream>>>(w2, wT, 5632, 2048);
  gemm_mt64<5><<<dim3(16, 64), 256, 0, stream>>>(h, wT, outp, nullptr, x1b, 4096, 2048, 5632);
}